// Round 9
// baseline (282.366 us; speedup 1.0000x reference)
//
#include <hip/hip_runtime.h>
#include <math.h>
#include <stdint.h>

// ---------------------------------------------------------------------------
// SpatialDecoder: 3x { h = x @ W^T ; GAT edge softmax over dst ; mean ; ELU }
// NT = 32768 nodes, C = H = 256, E = 262144 edges.
// This round: barrier-free GEMM. W held entirely in registers per wave
// (32-col slice = 16 frags), X A-frags loaded straight from global (L1/L2
// shared across the block's 8 waves). No LDS, no barriers in the K-loop.
// ---------------------------------------------------------------------------

typedef float f32x4 __attribute__((ext_vector_type(4)));
typedef _Float16 f16x8 __attribute__((ext_vector_type(8)));
typedef _Float16 f16x4 __attribute__((ext_vector_type(4)));

// ------------------------- f32 -> f16 conversion ---------------------------

__global__ __launch_bounds__(256) void convert_f16(const float* __restrict__ src,
                                                   _Float16* __restrict__ dstp)
{
    const int i = (blockIdx.x * 256 + threadIdx.x) * 8;
    float4 a = *(const float4*)&src[i];
    float4 b = *(const float4*)&src[i + 4];
    f16x8 o = {(_Float16)a.x, (_Float16)a.y, (_Float16)a.z, (_Float16)a.w,
               (_Float16)b.x, (_Float16)b.y, (_Float16)b.z, (_Float16)b.w};
    *(f16x8*)&dstp[i] = o;
}

// ------------------------- fp16 MFMA GEMM + row dots -----------------------
// Hout(M,256) = X(M,256) @ Wh(256,256)^T ; si = Hout@a[:256], sj = Hout@a[256:]
// 256 blocks x 512 threads. Block owns 128 rows; wave w owns cols [w*32,w*32+32).

__global__ __launch_bounds__(512, 2) void gemm_f16(const _Float16* __restrict__ X,
                                                   const _Float16* __restrict__ Wh,
                                                   const float* __restrict__ avec,
                                                   _Float16* __restrict__ Hout,
                                                   float* __restrict__ si,
                                                   float* __restrict__ sj)
{
    __shared__ float Es[16][260];     // epilogue transpose buffer (16.6 KB)

    const int tid  = threadIdx.x;
    const int lane = tid & 63;
    const int w    = tid >> 6;        // wave id 0..7 -> 32-col slice
    const int ln   = lane & 15;
    const int kq   = lane >> 4;       // 0..3
    const int m0   = blockIdx.x * 128;

    // ---- preload W fragments: 2 col-frags x 8 K-steps, kept in VGPRs ----
    f16x8 wf[2][8];
#pragma unroll
    for (int ks = 0; ks < 8; ++ks)
#pragma unroll
        for (int j = 0; j < 2; ++j)
            wf[j][ks] = *(const f16x8*)&Wh[(size_t)(w * 32 + j * 16 + ln) * 256 + ks * 32 + kq * 8];

    // ---- main loop: no barriers, no LDS; X frags straight from global ----
    f32x4 acc[8][2] = {};
    const _Float16* Xb = X + (size_t)m0 * 256 + kq * 8;

    f16x8 xf[8];
#pragma unroll
    for (int i = 0; i < 8; ++i)
        xf[i] = *(const f16x8*)&Xb[(size_t)(i * 16 + ln) * 256];

#pragma unroll
    for (int ks = 0; ks < 8; ++ks) {
        f16x8 xn[8];
        if (ks < 7) {
#pragma unroll
            for (int i = 0; i < 8; ++i)
                xn[i] = *(const f16x8*)&Xb[(size_t)(i * 16 + ln) * 256 + (ks + 1) * 32];
        }
#pragma unroll
        for (int i = 0; i < 8; ++i)
#pragma unroll
            for (int j = 0; j < 2; ++j)
                acc[i][j] = __builtin_amdgcn_mfma_f32_16x16x32_f16(xf[i], wf[j][ks], acc[i][j], 0, 0, 0);
        if (ks < 7) {
#pragma unroll
            for (int i = 0; i < 8; ++i) xf[i] = xn[i];
        }
    }

    // ---- epilogue: LDS transpose per 16-row group, f16 store + fused dots ----
    const int er = tid >> 5;          // 0..15 (row within 16-group)
    const int ec = tid & 31;          // 0..31 (8-col chunk)
    for (int i = 0; i < 8; ++i) {
#pragma unroll
        for (int j = 0; j < 2; ++j) {
            const int col = w * 32 + j * 16 + ln;
#pragma unroll
            for (int q = 0; q < 4; ++q)
                Es[kq * 4 + q][col] = acc[i][j][q];
        }
        __syncthreads();
        const int grow = m0 + i * 16 + er;
        const int c0 = ec * 8;
        f32x4 v0 = *(const f32x4*)&Es[er][c0];
        f32x4 v1 = *(const f32x4*)&Es[er][c0 + 4];
        f16x8 ho = {(_Float16)v0[0], (_Float16)v0[1], (_Float16)v0[2], (_Float16)v0[3],
                    (_Float16)v1[0], (_Float16)v1[1], (_Float16)v1[2], (_Float16)v1[3]};
        *(f16x8*)&Hout[(size_t)grow * 256 + c0] = ho;

        f32x4 al0 = *(const f32x4*)&avec[c0];
        f32x4 al1 = *(const f32x4*)&avec[c0 + 4];
        f32x4 ah0 = *(const f32x4*)&avec[256 + c0];
        f32x4 ah1 = *(const f32x4*)&avec[256 + c0 + 4];
        float d0 = v0[0]*al0[0] + v0[1]*al0[1] + v0[2]*al0[2] + v0[3]*al0[3]
                 + v1[0]*al1[0] + v1[1]*al1[1] + v1[2]*al1[2] + v1[3]*al1[3];
        float d1 = v0[0]*ah0[0] + v0[1]*ah0[1] + v0[2]*ah0[2] + v0[3]*ah0[3]
                 + v1[0]*ah1[0] + v1[1]*ah1[1] + v1[2]*ah1[2] + v1[3]*ah1[3];
#pragma unroll
        for (int d = 16; d; d >>= 1) {
            d0 += __shfl_xor(d0, d);
            d1 += __shfl_xor(d1, d);
        }
        if (ec == 0) { si[grow] = d0; sj[grow] = d1; }
        __syncthreads();
    }
}

// ------------------------- edge preprocessing ------------------------------

__global__ void zero_int(int* p, int n)
{
    int i = blockIdx.x * blockDim.x + threadIdx.x;
    if (i < n) p[i] = 0;
}

__global__ void hist_kernel(const int* __restrict__ dst, int* __restrict__ cnt, int E)
{
    int e = blockIdx.x * blockDim.x + threadIdx.x;
    if (e < E) atomicAdd(&cnt[dst[e]], 1);
}

__global__ __launch_bounds__(1024) void scan_part(const int* __restrict__ cnt,
                                                  int* __restrict__ off,
                                                  int* __restrict__ bsum)
{
    __shared__ int buf[1024];
    const int tid = threadIdx.x;
    const int g = blockIdx.x * 1024 + tid;
    int v = cnt[g];
    buf[tid] = v;
    __syncthreads();
#pragma unroll
    for (int d = 1; d < 1024; d <<= 1) {
        int t = (tid >= d) ? buf[tid - d] : 0;
        __syncthreads();
        buf[tid] += t;
        __syncthreads();
    }
    off[g] = buf[tid] - v;                      // local exclusive
    if (tid == 1023) bsum[blockIdx.x] = buf[1023];
}

__global__ void scan_bsum(int* bsum, int nb)
{
    __shared__ int b[64];
    const int tid = threadIdx.x;                // 64 threads
    b[tid] = (tid < nb) ? bsum[tid] : 0;
    __syncthreads();
    if (tid == 0) {
        int a = 0;
        for (int i = 0; i < nb; ++i) { int t = b[i]; b[i] = a; a += t; }
    }
    __syncthreads();
    if (tid < nb) bsum[tid] = b[tid];
}

__global__ __launch_bounds__(1024) void scan_add(const int* __restrict__ bsum,
                                                 int* __restrict__ off,
                                                 int* __restrict__ cursor,
                                                 int NT, int E)
{
    const int tid = threadIdx.x;
    const int g = blockIdx.x * 1024 + tid;
    int v = off[g] + bsum[blockIdx.x];
    off[g] = v;
    cursor[g] = v;
    if (g == 0) off[NT] = E;
}

__global__ void scatter_kernel(const int* __restrict__ src,
                               const int* __restrict__ dst,
                               int* __restrict__ cursor,
                               int* __restrict__ ssrc, int E)
{
    int e = blockIdx.x * blockDim.x + threadIdx.x;
    if (e < E) {
        int p = atomicAdd(&cursor[dst[e]], 1);
        ssrc[p] = src[e];
    }
}

// ------------------------- per-node softmax + aggregate --------------------
// One wave per node. Fast path (deg<=64): lane=edge score+softmax in one pass,
// then x4-unrolled row gather with readlane-broadcast (src,weight).
// F16OUT=1: write f16 (next layer's GEMM input). F16OUT=0: write f32 (d_out).

__device__ __forceinline__ float bcast_f(float x, int l)
{
    return __uint_as_float(__builtin_amdgcn_readlane(__float_as_uint(x), l));
}

template <int F16OUT>
__global__ __launch_bounds__(256) void aggregate(const _Float16* __restrict__ Hh,
                                                 const float* __restrict__ si,
                                                 const float* __restrict__ sj,
                                                 const int* __restrict__ off,
                                                 const int* __restrict__ ssrc,
                                                 void* __restrict__ outv,
                                                 int n_nodes)
{
    const int v = (blockIdx.x * 256 + threadIdx.x) >> 6;   // one wave per node
    const int lane = threadIdx.x & 63;
    if (v >= n_nodes) return;

    const int e0 = off[v], e1 = off[v + 1];
    const int deg = e1 - e0;
    f32x4 acc = {0.f, 0.f, 0.f, 0.f};

    if (deg > 0 && deg <= 64) {
        const float siv = si[v];
        // edge-parallel score: lane l owns edge e0+l
        const int idx = e0 + lane;
        const bool on = idx < e1;
        int s = 0;
        float scv = -1e30f;
        if (on) {
            s = ssrc[idx];
            float t = siv + sj[s];
            scv = (t >= 0.f) ? t : 0.2f * t;
        }
        float m = scv;
#pragma unroll
        for (int d = 32; d; d >>= 1) m = fmaxf(m, __shfl_xor(m, d));
        float wv = on ? __expf(scv - m) : 0.f;
        float den = wv;
#pragma unroll
        for (int d = 32; d; d >>= 1) den += __shfl_xor(den, d);

        // column-parallel gather: lane covers cols [lane*4, lane*4+4)
        const int c4 = lane * 4;
        for (int eo = 0; eo < deg; eo += 4) {
            const int l1 = (eo + 1 < 63) ? eo + 1 : 63;
            const int l2 = (eo + 2 < 63) ? eo + 2 : 63;
            const int l3 = (eo + 3 < 63) ? eo + 3 : 63;
            const int s0 = __builtin_amdgcn_readlane(s, eo);
            const int s1 = __builtin_amdgcn_readlane(s, l1);
            const int s2 = __builtin_amdgcn_readlane(s, l2);
            const int s3 = __builtin_amdgcn_readlane(s, l3);
            const float w0 = bcast_f(wv, eo);
            const float w1 = bcast_f(wv, l1);
            const float w2 = bcast_f(wv, l2);
            const float w3 = bcast_f(wv, l3);
            // 4 independent 512B row loads in flight
            const f16x4 v0 = *(const f16x4*)&Hh[(size_t)s0 * 256 + c4];
            const f16x4 v1 = *(const f16x4*)&Hh[(size_t)s1 * 256 + c4];
            const f16x4 v2 = *(const f16x4*)&Hh[(size_t)s2 * 256 + c4];
            const f16x4 v3 = *(const f16x4*)&Hh[(size_t)s3 * 256 + c4];
#pragma unroll
            for (int q = 0; q < 4; ++q)
                acc[q] += w0 * (float)v0[q] + w1 * (float)v1[q]
                        + w2 * (float)v2[q] + w3 * (float)v3[q];
        }
        const float inv = 1.f / (den * (float)deg);
#pragma unroll
        for (int q = 0; q < 4; ++q) acc[q] *= inv;
    } else if (deg > 64) {
        // generic fallback (rare): 3-pass lane-strided
        const float siv = si[v];
        float m = -1e30f;
        for (int b = e0 + lane; b < e1; b += 64) {
            float t = siv + sj[ssrc[b]];
            t = (t >= 0.f) ? t : 0.2f * t;
            m = fmaxf(m, t);
        }
#pragma unroll
        for (int d = 32; d; d >>= 1) m = fmaxf(m, __shfl_xor(m, d));
        float den = 0.f;
        for (int b = e0 + lane; b < e1; b += 64) {
            float t = siv + sj[ssrc[b]];
            t = (t >= 0.f) ? t : 0.2f * t;
            den += __expf(t - m);
        }
#pragma unroll
        for (int d = 32; d; d >>= 1) den += __shfl_xor(den, d);
        for (int e = e0; e < e1; ++e) {
            const int s = ssrc[e];
            float t = siv + sj[s];
            t = (t >= 0.f) ? t : 0.2f * t;
            const float wgt = __expf(t - m);
            const f16x4 hv = *(const f16x4*)&Hh[(size_t)s * 256 + lane * 4];
#pragma unroll
            for (int q = 0; q < 4; ++q) acc[q] += wgt * (float)hv[q];
        }
        const float inv = 1.f / (den * (float)deg);
#pragma unroll
        for (int q = 0; q < 4; ++q) acc[q] *= inv;
    }

    // ELU + store
    float4 o;
    o.x = (acc[0] > 0.f) ? acc[0] : (__expf(acc[0]) - 1.f);
    o.y = (acc[1] > 0.f) ? acc[1] : (__expf(acc[1]) - 1.f);
    o.z = (acc[2] > 0.f) ? acc[2] : (__expf(acc[2]) - 1.f);
    o.w = (acc[3] > 0.f) ? acc[3] : (__expf(acc[3]) - 1.f);
    if (F16OUT) {
        f16x4 oh = {(_Float16)o.x, (_Float16)o.y, (_Float16)o.z, (_Float16)o.w};
        *(f16x4*)&((_Float16*)outv)[(size_t)v * 256 + lane * 4] = oh;
    } else {
        *(float4*)&((float*)outv)[(size_t)v * 256 + lane * 4] = o;
    }
}

// ---------------------------------------------------------------------------

extern "C" void kernel_launch(void* const* d_in, const int* in_sizes, int n_in,
                              void* d_out, int out_size, void* d_ws, size_t ws_size,
                              hipStream_t stream)
{
    const float* x0 = (const float*)d_in[0];
    const int*   ei = (const int*)d_in[1];      // (2,E) int32: row0=src, row1=dst
    const float* Ws[3] = {(const float*)d_in[2], (const float*)d_in[4], (const float*)d_in[6]};
    const float* as[3] = {(const float*)d_in[3], (const float*)d_in[5], (const float*)d_in[7]};
    float* out = (float*)d_out;

    const int NT = in_sizes[0] / 256;   // 32768
    const int E  = in_sizes[1] / 2;     // 262144
    const int* srcI = ei;
    const int* dstI = ei + E;

    // workspace layout (~34 MB)
    _Float16* Hh = (_Float16*)d_ws;                 // NT*256 f16
    _Float16* Xh = Hh + (size_t)NT * 256;           // NT*256 f16 (layer input)
    float* si    = (float*)(Xh + (size_t)NT * 256);
    float* sj    = si + NT;
    int* cnt     = (int*)(sj + NT);
    int* off     = cnt + NT;            // NT+1 entries
    int* cursor  = off + NT + 1;
    int* ssrc    = cursor + NT;         // E entries
    int* bsum    = ssrc + E;            // 32 entries (round up 64)
    _Float16* Wh = (_Float16*)(((uintptr_t)(bsum + 64) + 255) & ~(uintptr_t)255);

    // weight + input conversion (f32 -> f16)
    for (int l = 0; l < 3; ++l)
        convert_f16<<<32, 256, 0, stream>>>(Ws[l], Wh + (size_t)l * 65536);
    convert_f16<<<NT * 256 / 2048, 256, 0, stream>>>(x0, Xh);

    // edge preprocessing (layer-invariant)
    zero_int<<<(NT + 255) / 256, 256, 0, stream>>>(cnt, NT);
    hist_kernel<<<(E + 255) / 256, 256, 0, stream>>>(dstI, cnt, E);
    scan_part<<<NT / 1024, 1024, 0, stream>>>(cnt, off, bsum);
    scan_bsum<<<1, 64, 0, stream>>>(bsum, NT / 1024);
    scan_add<<<NT / 1024, 1024, 0, stream>>>(bsum, off, cursor, NT, E);
    scatter_kernel<<<(E + 255) / 256, 256, 0, stream>>>(srcI, dstI, cursor, ssrc, E);

    for (int l = 0; l < 3; ++l) {
        gemm_f16<<<NT / 128, 512, 0, stream>>>(Xh, Wh + (size_t)l * 65536, as[l], Hh, si, sj);
        if (l < 2)
            aggregate<1><<<NT / 4, 256, 0, stream>>>(Hh, si, sj, off, ssrc, (void*)Xh, NT);
        else
            aggregate<0><<<NT / 4, 256, 0, stream>>>(Hh, si, sj, off, ssrc, (void*)out, NT);
    }
}

// Round 10
// 248.965 us; speedup vs baseline: 1.1342x; 1.1342x over previous
//
#include <hip/hip_runtime.h>
#include <math.h>
#include <stdint.h>

// ---------------------------------------------------------------------------
// SpatialDecoder: 3x { h = x @ W^T ; GAT edge softmax over dst ; mean ; ELU }
// NT = 32768 nodes, C = H = 256, E = 262144 edges.
// This round: revert to LDS-staged GEMM (round-8 skeleton) with BM=128/BK=64
// (half the barriers, 32 MFMA per sync per wave) and T2 XOR-swizzled LDS
// (byte ^= (row&7)<<4) instead of padding -> uniform bank use on ds_read_b128.
// ---------------------------------------------------------------------------

typedef float f32x4 __attribute__((ext_vector_type(4)));
typedef _Float16 f16x8 __attribute__((ext_vector_type(8)));
typedef _Float16 f16x4 __attribute__((ext_vector_type(4)));

// ------------------------- f32 -> f16 conversion ---------------------------

__global__ __launch_bounds__(256) void convert_f16(const float* __restrict__ src,
                                                   _Float16* __restrict__ dstp)
{
    const int i = (blockIdx.x * 256 + threadIdx.x) * 8;
    float4 a = *(const float4*)&src[i];
    float4 b = *(const float4*)&src[i + 4];
    f16x8 o = {(_Float16)a.x, (_Float16)a.y, (_Float16)a.z, (_Float16)a.w,
               (_Float16)b.x, (_Float16)b.y, (_Float16)b.z, (_Float16)b.w};
    *(f16x8*)&dstp[i] = o;
}

// ------------------------- fp16 MFMA GEMM + row dots -----------------------
// Hout(M,256) = X(M,256) @ Wh(256,256)^T ; si = Hout@a[:256], sj = Hout@a[256:]
// 256 blocks x 512 threads. Block owns 128 rows; wave (wr,wc) owns 64x64 tile.

#define SWZ(row, byte) ((byte) ^ (((row) & 7) << 4))

__global__ __launch_bounds__(512) void gemm_f16(const _Float16* __restrict__ X,
                                                const _Float16* __restrict__ Wh,
                                                const float* __restrict__ avec,
                                                _Float16* __restrict__ Hout,
                                                float* __restrict__ si,
                                                float* __restrict__ sj)
{
    // Xs: 128 rows x 128B = 16KB at offset 0; Wl: 256 rows x 128B = 32KB at 16KB.
    // Epilogue Es[16][260] f32 (16.6KB) aliases Xs region (separated by barriers).
    __shared__ __align__(16) unsigned char smem[49152];
    char* Xs = (char*)smem;
    char* Wl = (char*)smem + 16384;
    float (*Es)[260] = (float (*)[260])smem;

    const int tid  = threadIdx.x;
    const int lane = tid & 63;
    const int w    = tid >> 6;        // wave 0..7
    const int wr   = w >> 2;          // row half (64 rows)
    const int wc   = w & 3;           // col quarter (64 cols)
    const int ln   = lane & 15;
    const int kq   = lane >> 4;       // 0..3
    const int m0   = blockIdx.x * 128;

    // staging indices
    const int xr = tid >> 2;          // X row 0..127
    const int xc = tid & 3;           // 32B chunk within 128B row-slice
    const int wrow = tid >> 1;        // W row 0..255
    const int wcb  = (tid & 1) * 64;  // byte offset within 128B row-slice

    const _Float16* Xg = X  + (size_t)(m0 + xr) * 256 + xc * 16;
    const _Float16* Wg = Wh + (size_t)wrow * 256 + wcb / 2;
    char* XsW = Xs + SWZ(xr, xr * 128 + xc * 32);         // xor const per thread
    char* XsW2 = Xs + SWZ(xr, xr * 128 + xc * 32 + 16);
    char* WlW0 = Wl + SWZ(wrow, wrow * 128 + wcb + 0);
    char* WlW1 = Wl + SWZ(wrow, wrow * 128 + wcb + 16);
    char* WlW2 = Wl + SWZ(wrow, wrow * 128 + wcb + 32);
    char* WlW3 = Wl + SWZ(wrow, wrow * 128 + wcb + 48);

    f32x4 acc[4][4] = {};

    for (int k0 = 0; k0 < 256; k0 += 64) {
        // ---- stage: X 128x64f16, W 256x64f16 (6 x 16B per thread) ----
        f16x8 x0 = *(const f16x8*)&Xg[k0];
        f16x8 x1 = *(const f16x8*)&Xg[k0 + 8];
        f16x8 w0 = *(const f16x8*)&Wg[k0];
        f16x8 w1 = *(const f16x8*)&Wg[k0 + 8];
        f16x8 w2 = *(const f16x8*)&Wg[k0 + 16];
        f16x8 w3 = *(const f16x8*)&Wg[k0 + 24];
        *(f16x8*)XsW  = x0;  *(f16x8*)XsW2 = x1;
        *(f16x8*)WlW0 = w0;  *(f16x8*)WlW1 = w1;
        *(f16x8*)WlW2 = w2;  *(f16x8*)WlW3 = w3;
        __syncthreads();

        // ---- compute: 2 kk-halves x 16 MFMA ----
#pragma unroll
        for (int kk = 0; kk < 2; ++kk) {
            f16x8 af[4], bf[4];
#pragma unroll
            for (int i = 0; i < 4; ++i) {
                const int row = wr * 64 + i * 16 + ln;
                af[i] = *(const f16x8*)(Xs + SWZ(row, row * 128 + kk * 64 + kq * 16));
            }
#pragma unroll
            for (int j = 0; j < 4; ++j) {
                const int row = wc * 64 + j * 16 + ln;
                bf[j] = *(const f16x8*)(Wl + SWZ(row, row * 128 + kk * 64 + kq * 16));
            }
#pragma unroll
            for (int i = 0; i < 4; ++i)
#pragma unroll
                for (int j = 0; j < 4; ++j)
                    acc[i][j] = __builtin_amdgcn_mfma_f32_16x16x32_f16(af[i], bf[j], acc[i][j], 0, 0, 0);
        }
        __syncthreads();
    }

    // ---- epilogue: per 16-row group, LDS transpose + f16 store + fused dots ----
    const int er = tid >> 5;          // 0..15
    const int ec = tid & 31;          // 0..31
    for (int g = 0; g < 8; ++g) {
        if (wr == (g >> 2)) {
            const int i = g & 3;
#pragma unroll
            for (int j = 0; j < 4; ++j) {
                const int col = wc * 64 + j * 16 + ln;
#pragma unroll
                for (int q = 0; q < 4; ++q)
                    Es[kq * 4 + q][col] = acc[i][j][q];
            }
        }
        __syncthreads();
        const int grow = m0 + g * 16 + er;
        const int c0 = ec * 8;
        f32x4 v0 = *(const f32x4*)&Es[er][c0];
        f32x4 v1 = *(const f32x4*)&Es[er][c0 + 4];
        f16x8 ho = {(_Float16)v0[0], (_Float16)v0[1], (_Float16)v0[2], (_Float16)v0[3],
                    (_Float16)v1[0], (_Float16)v1[1], (_Float16)v1[2], (_Float16)v1[3]};
        *(f16x8*)&Hout[(size_t)grow * 256 + c0] = ho;

        f32x4 al0 = *(const f32x4*)&avec[c0];
        f32x4 al1 = *(const f32x4*)&avec[c0 + 4];
        f32x4 ah0 = *(const f32x4*)&avec[256 + c0];
        f32x4 ah1 = *(const f32x4*)&avec[256 + c0 + 4];
        float d0 = v0[0]*al0[0] + v0[1]*al0[1] + v0[2]*al0[2] + v0[3]*al0[3]
                 + v1[0]*al1[0] + v1[1]*al1[1] + v1[2]*al1[2] + v1[3]*al1[3];
        float d1 = v0[0]*ah0[0] + v0[1]*ah0[1] + v0[2]*ah0[2] + v0[3]*ah0[3]
                 + v1[0]*ah1[0] + v1[1]*ah1[1] + v1[2]*ah1[2] + v1[3]*ah1[3];
#pragma unroll
        for (int d = 16; d; d >>= 1) {
            d0 += __shfl_xor(d0, d);
            d1 += __shfl_xor(d1, d);
        }
        if (ec == 0) { si[grow] = d0; sj[grow] = d1; }
        __syncthreads();
    }
}

// ------------------------- edge preprocessing ------------------------------

__global__ void zero_int(int* p, int n)
{
    int i = blockIdx.x * blockDim.x + threadIdx.x;
    if (i < n) p[i] = 0;
}

__global__ void hist_kernel(const int* __restrict__ dst, int* __restrict__ cnt, int E)
{
    int e = blockIdx.x * blockDim.x + threadIdx.x;
    if (e < E) atomicAdd(&cnt[dst[e]], 1);
}

__global__ __launch_bounds__(1024) void scan_part(const int* __restrict__ cnt,
                                                  int* __restrict__ off,
                                                  int* __restrict__ bsum)
{
    __shared__ int buf[1024];
    const int tid = threadIdx.x;
    const int g = blockIdx.x * 1024 + tid;
    int v = cnt[g];
    buf[tid] = v;
    __syncthreads();
#pragma unroll
    for (int d = 1; d < 1024; d <<= 1) {
        int t = (tid >= d) ? buf[tid - d] : 0;
        __syncthreads();
        buf[tid] += t;
        __syncthreads();
    }
    off[g] = buf[tid] - v;                      // local exclusive
    if (tid == 1023) bsum[blockIdx.x] = buf[1023];
}

__global__ void scan_bsum(int* bsum, int nb)
{
    __shared__ int b[64];
    const int tid = threadIdx.x;                // 64 threads
    b[tid] = (tid < nb) ? bsum[tid] : 0;
    __syncthreads();
    if (tid == 0) {
        int a = 0;
        for (int i = 0; i < nb; ++i) { int t = b[i]; b[i] = a; a += t; }
    }
    __syncthreads();
    if (tid < nb) bsum[tid] = b[tid];
}

__global__ __launch_bounds__(1024) void scan_add(const int* __restrict__ bsum,
                                                 int* __restrict__ off,
                                                 int* __restrict__ cursor,
                                                 int NT, int E)
{
    const int tid = threadIdx.x;
    const int g = blockIdx.x * 1024 + tid;
    int v = off[g] + bsum[blockIdx.x];
    off[g] = v;
    cursor[g] = v;
    if (g == 0) off[NT] = E;
}

__global__ void scatter_kernel(const int* __restrict__ src,
                               const int* __restrict__ dst,
                               int* __restrict__ cursor,
                               int* __restrict__ ssrc, int E)
{
    int e = blockIdx.x * blockDim.x + threadIdx.x;
    if (e < E) {
        int p = atomicAdd(&cursor[dst[e]], 1);
        ssrc[p] = src[e];
    }
}

// ------------------------- per-node softmax + aggregate --------------------
// One wave per node. Fast path (deg<=64): lane=edge score+softmax in one pass,
// then x4-unrolled row gather with readlane-broadcast (src,weight).
// F16OUT=1: write f16 (next layer's GEMM input). F16OUT=0: write f32 (d_out).

__device__ __forceinline__ float bcast_f(float x, int l)
{
    return __uint_as_float(__builtin_amdgcn_readlane(__float_as_uint(x), l));
}

template <int F16OUT>
__global__ __launch_bounds__(256) void aggregate(const _Float16* __restrict__ Hh,
                                                 const float* __restrict__ si,
                                                 const float* __restrict__ sj,
                                                 const int* __restrict__ off,
                                                 const int* __restrict__ ssrc,
                                                 void* __restrict__ outv,
                                                 int n_nodes)
{
    const int v = (blockIdx.x * 256 + threadIdx.x) >> 6;   // one wave per node
    const int lane = threadIdx.x & 63;
    if (v >= n_nodes) return;

    const int e0 = off[v], e1 = off[v + 1];
    const int deg = e1 - e0;
    f32x4 acc = {0.f, 0.f, 0.f, 0.f};

    if (deg > 0 && deg <= 64) {
        const float siv = si[v];
        // edge-parallel score: lane l owns edge e0+l
        const int idx = e0 + lane;
        const bool on = idx < e1;
        int s = 0;
        float scv = -1e30f;
        if (on) {
            s = ssrc[idx];
            float t = siv + sj[s];
            scv = (t >= 0.f) ? t : 0.2f * t;
        }
        float m = scv;
#pragma unroll
        for (int d = 32; d; d >>= 1) m = fmaxf(m, __shfl_xor(m, d));
        float wv = on ? __expf(scv - m) : 0.f;
        float den = wv;
#pragma unroll
        for (int d = 32; d; d >>= 1) den += __shfl_xor(den, d);

        // column-parallel gather: lane covers cols [lane*4, lane*4+4)
        const int c4 = lane * 4;
        for (int eo = 0; eo < deg; eo += 4) {
            const int l1 = (eo + 1 < 63) ? eo + 1 : 63;
            const int l2 = (eo + 2 < 63) ? eo + 2 : 63;
            const int l3 = (eo + 3 < 63) ? eo + 3 : 63;
            const int s0 = __builtin_amdgcn_readlane(s, eo);
            const int s1 = __builtin_amdgcn_readlane(s, l1);
            const int s2 = __builtin_amdgcn_readlane(s, l2);
            const int s3 = __builtin_amdgcn_readlane(s, l3);
            const float w0 = bcast_f(wv, eo);
            const float w1 = bcast_f(wv, l1);
            const float w2 = bcast_f(wv, l2);
            const float w3 = bcast_f(wv, l3);
            // 4 independent 512B row loads in flight
            const f16x4 v0 = *(const f16x4*)&Hh[(size_t)s0 * 256 + c4];
            const f16x4 v1 = *(const f16x4*)&Hh[(size_t)s1 * 256 + c4];
            const f16x4 v2 = *(const f16x4*)&Hh[(size_t)s2 * 256 + c4];
            const f16x4 v3 = *(const f16x4*)&Hh[(size_t)s3 * 256 + c4];
#pragma unroll
            for (int q = 0; q < 4; ++q)
                acc[q] += w0 * (float)v0[q] + w1 * (float)v1[q]
                        + w2 * (float)v2[q] + w3 * (float)v3[q];
        }
        const float inv = 1.f / (den * (float)deg);
#pragma unroll
        for (int q = 0; q < 4; ++q) acc[q] *= inv;
    } else if (deg > 64) {
        // generic fallback (rare): 3-pass lane-strided
        const float siv = si[v];
        float m = -1e30f;
        for (int b = e0 + lane; b < e1; b += 64) {
            float t = siv + sj[ssrc[b]];
            t = (t >= 0.f) ? t : 0.2f * t;
            m = fmaxf(m, t);
        }
#pragma unroll
        for (int d = 32; d; d >>= 1) m = fmaxf(m, __shfl_xor(m, d));
        float den = 0.f;
        for (int b = e0 + lane; b < e1; b += 64) {
            float t = siv + sj[ssrc[b]];
            t = (t >= 0.f) ? t : 0.2f * t;
            den += __expf(t - m);
        }
#pragma unroll
        for (int d = 32; d; d >>= 1) den += __shfl_xor(den, d);
        for (int e = e0; e < e1; ++e) {
            const int s = ssrc[e];
            float t = siv + sj[s];
            t = (t >= 0.f) ? t : 0.2f * t;
            const float wgt = __expf(t - m);
            const f16x4 hv = *(const f16x4*)&Hh[(size_t)s * 256 + lane * 4];
#pragma unroll
            for (int q = 0; q < 4; ++q) acc[q] += wgt * (float)hv[q];
        }
        const float inv = 1.f / (den * (float)deg);
#pragma unroll
        for (int q = 0; q < 4; ++q) acc[q] *= inv;
    }

    // ELU + store
    float4 o;
    o.x = (acc[0] > 0.f) ? acc[0] : (__expf(acc[0]) - 1.f);
    o.y = (acc[1] > 0.f) ? acc[1] : (__expf(acc[1]) - 1.f);
    o.z = (acc[2] > 0.f) ? acc[2] : (__expf(acc[2]) - 1.f);
    o.w = (acc[3] > 0.f) ? acc[3] : (__expf(acc[3]) - 1.f);
    if (F16OUT) {
        f16x4 oh = {(_Float16)o.x, (_Float16)o.y, (_Float16)o.z, (_Float16)o.w};
        *(f16x4*)&((_Float16*)outv)[(size_t)v * 256 + lane * 4] = oh;
    } else {
        *(float4*)&((float*)outv)[(size_t)v * 256 + lane * 4] = o;
    }
}

// ---------------------------------------------------------------------------

extern "C" void kernel_launch(void* const* d_in, const int* in_sizes, int n_in,
                              void* d_out, int out_size, void* d_ws, size_t ws_size,
                              hipStream_t stream)
{
    const float* x0 = (const float*)d_in[0];
    const int*   ei = (const int*)d_in[1];      // (2,E) int32: row0=src, row1=dst
    const float* Ws[3] = {(const float*)d_in[2], (const float*)d_in[4], (const float*)d_in[6]};
    const float* as[3] = {(const float*)d_in[3], (const float*)d_in[5], (const float*)d_in[7]};
    float* out = (float*)d_out;

    const int NT = in_sizes[0] / 256;   // 32768
    const int E  = in_sizes[1] / 2;     // 262144
    const int* srcI = ei;
    const int* dstI = ei + E;

    // workspace layout (~34 MB)
    _Float16* Hh = (_Float16*)d_ws;                 // NT*256 f16
    _Float16* Xh = Hh + (size_t)NT * 256;           // NT*256 f16 (layer input)
    float* si    = (float*)(Xh + (size_t)NT * 256);
    float* sj    = si + NT;
    int* cnt     = (int*)(sj + NT);
    int* off     = cnt + NT;            // NT+1 entries
    int* cursor  = off + NT + 1;
    int* ssrc    = cursor + NT;         // E entries
    int* bsum    = ssrc + E;            // 32 entries (round up 64)
    _Float16* Wh = (_Float16*)(((uintptr_t)(bsum + 64) + 255) & ~(uintptr_t)255);

    // weight + input conversion (f32 -> f16)
    for (int l = 0; l < 3; ++l)
        convert_f16<<<32, 256, 0, stream>>>(Ws[l], Wh + (size_t)l * 65536);
    convert_f16<<<NT * 256 / 2048, 256, 0, stream>>>(x0, Xh);

    // edge preprocessing (layer-invariant)
    zero_int<<<(NT + 255) / 256, 256, 0, stream>>>(cnt, NT);
    hist_kernel<<<(E + 255) / 256, 256, 0, stream>>>(dstI, cnt, E);
    scan_part<<<NT / 1024, 1024, 0, stream>>>(cnt, off, bsum);
    scan_bsum<<<1, 64, 0, stream>>>(bsum, NT / 1024);
    scan_add<<<NT / 1024, 1024, 0, stream>>>(bsum, off, cursor, NT, E);
    scatter_kernel<<<(E + 255) / 256, 256, 0, stream>>>(srcI, dstI, cursor, ssrc, E);

    for (int l = 0; l < 3; ++l) {
        gemm_f16<<<NT / 128, 512, 0, stream>>>(Xh, Wh + (size_t)l * 65536, as[l], Hh, si, sj);
        if (l < 2)
            aggregate<1><<<NT / 4, 256, 0, stream>>>(Hh, si, sj, off, ssrc, (void*)Xh, NT);
        else
            aggregate<0><<<NT / 4, 256, 0, stream>>>(Hh, si, sj, off, ssrc, (void*)out, NT);
    }
}

// Round 13
// 241.496 us; speedup vs baseline: 1.1692x; 1.0309x over previous
//
#include <hip/hip_runtime.h>
#include <math.h>
#include <stdint.h>

// ---------------------------------------------------------------------------
// SpatialDecoder: 3x { h = x @ W^T ; GAT edge softmax over dst ; mean ; ELU }
// NT = 32768 nodes, C = H = 256, E = 262144 edges.
// This round: (1) GEMM 2-phase double-buffered pipeline — issue next K-tile's
// global loads BEFORE compute, ds_write after, ONE barrier per K-tile (8->5);
// (2) all f32->f16 converts merged into one launch.
// ---------------------------------------------------------------------------

typedef float f32x4 __attribute__((ext_vector_type(4)));
typedef _Float16 f16x8 __attribute__((ext_vector_type(8)));
typedef _Float16 f16x4 __attribute__((ext_vector_type(4)));

// ------------------------- merged f32 -> f16 conversion --------------------
// Converts x0 (nx elems) -> Xh, then W0|W1|W2 (65536 each) -> Wh.

__global__ __launch_bounds__(256) void convert_all(const float* __restrict__ x0,
                                                   _Float16* __restrict__ Xh, int nx,
                                                   const float* __restrict__ W0,
                                                   const float* __restrict__ W1,
                                                   const float* __restrict__ W2,
                                                   _Float16* __restrict__ Wh)
{
    const int i = (blockIdx.x * 256 + threadIdx.x) * 8;
    const float* src;
    _Float16* dstp;
    int off;
    if (i < nx) { src = x0; dstp = Xh; off = i; }
    else {
        const int j = i - nx;
        src = (j < 65536) ? W0 : ((j < 131072) ? W1 : W2);
        off = j & 65535;
        dstp = Wh + (j - off);      // Wh + layer*65536
    }
    float4 a = *(const float4*)&src[off];
    float4 b = *(const float4*)&src[off + 4];
    f16x8 o = {(_Float16)a.x, (_Float16)a.y, (_Float16)a.z, (_Float16)a.w,
               (_Float16)b.x, (_Float16)b.y, (_Float16)b.z, (_Float16)b.w};
    *(f16x8*)&dstp[off] = o;
}

// ------------------------- fp16 MFMA GEMM + row dots -----------------------
// Hout(M,256) = X(M,256) @ Wh(256,256)^T ; si = Hout@a[:256], sj = Hout@a[256:]
// 256 blocks x 512 threads. Block owns 128 rows; wave (wr,wc) owns 64x64 tile.
// Double-buffered LDS (2 x 48KB), 2-phase pipeline, 1 barrier per K-tile.

#define SWZ(row, byte) ((byte) ^ (((row) & 7) << 4))

__global__ __launch_bounds__(512) void gemm_f16(const _Float16* __restrict__ X,
                                                const _Float16* __restrict__ Wh,
                                                const float* __restrict__ avec,
                                                _Float16* __restrict__ Hout,
                                                float* __restrict__ si,
                                                float* __restrict__ sj)
{
    // buffer b at smem + b*49152: Xs 128x128B (16KB) then Wl 256x128B (32KB).
    // Epilogue Es[16][260] f32 aliases buffer 0 (after final barrier).
    __shared__ __align__(16) unsigned char smem[98304];
    float (*Es)[260] = (float (*)[260])smem;

    const int tid  = threadIdx.x;
    const int lane = tid & 63;
    const int w    = tid >> 6;        // wave 0..7
    const int wr   = w >> 2;          // row half (64 rows)
    const int wc   = w & 3;           // col quarter (64 cols)
    const int ln   = lane & 15;
    const int kq   = lane >> 4;       // 0..3
    const int m0   = blockIdx.x * 128;

    // staging indices
    const int xr = tid >> 2;          // X row 0..127
    const int xc = tid & 3;           // 32B chunk within 128B row-slice
    const int wrow = tid >> 1;        // W row 0..255
    const int wcb  = (tid & 1) * 64;  // byte offset within 128B row-slice

    const _Float16* Xg = X  + (size_t)(m0 + xr) * 256 + xc * 16;
    const _Float16* Wg = Wh + (size_t)wrow * 256 + wcb / 2;
    const int xs0 = SWZ(xr, xr * 128 + xc * 32);
    const int xs1 = SWZ(xr, xr * 128 + xc * 32 + 16);
    const int wl0 = 16384 + SWZ(wrow, wrow * 128 + wcb + 0);
    const int wl1 = 16384 + SWZ(wrow, wrow * 128 + wcb + 16);
    const int wl2 = 16384 + SWZ(wrow, wrow * 128 + wcb + 32);
    const int wl3 = 16384 + SWZ(wrow, wrow * 128 + wcb + 48);

    f32x4 acc[4][4] = {};

    // ---- prologue: stage K-tile 0 into buffer 0 ----
    f16x8 x0 = *(const f16x8*)&Xg[0];
    f16x8 x1 = *(const f16x8*)&Xg[8];
    f16x8 w0 = *(const f16x8*)&Wg[0];
    f16x8 w1 = *(const f16x8*)&Wg[8];
    f16x8 w2 = *(const f16x8*)&Wg[16];
    f16x8 w3 = *(const f16x8*)&Wg[24];
    *(f16x8*)(smem + xs0) = x0;  *(f16x8*)(smem + xs1) = x1;
    *(f16x8*)(smem + wl0) = w0;  *(f16x8*)(smem + wl1) = w1;
    *(f16x8*)(smem + wl2) = w2;  *(f16x8*)(smem + wl3) = w3;
    __syncthreads();

#pragma unroll
    for (int t = 0; t < 4; ++t) {
        const int cb = (t & 1) * 49152;          // current buffer
        const int nb = ((t & 1) ^ 1) * 49152;    // next buffer
        // issue next tile's global loads EARLY (latency hides under MFMA)
        if (t < 3) {
            const int k0 = (t + 1) * 64;
            x0 = *(const f16x8*)&Xg[k0];
            x1 = *(const f16x8*)&Xg[k0 + 8];
            w0 = *(const f16x8*)&Wg[k0];
            w1 = *(const f16x8*)&Wg[k0 + 8];
            w2 = *(const f16x8*)&Wg[k0 + 16];
            w3 = *(const f16x8*)&Wg[k0 + 24];
        }
        // compute current tile: 2 kk-halves x 16 MFMA
#pragma unroll
        for (int kk = 0; kk < 2; ++kk) {
            f16x8 af[4], bf[4];
#pragma unroll
            for (int i = 0; i < 4; ++i) {
                const int row = wr * 64 + i * 16 + ln;
                af[i] = *(const f16x8*)(smem + cb + SWZ(row, row * 128 + kk * 64 + kq * 16));
            }
#pragma unroll
            for (int j = 0; j < 4; ++j) {
                const int row = wc * 64 + j * 16 + ln;
                bf[j] = *(const f16x8*)(smem + cb + 16384 + SWZ(row, row * 128 + kk * 64 + kq * 16));
            }
#pragma unroll
            for (int i = 0; i < 4; ++i)
#pragma unroll
                for (int j = 0; j < 4; ++j)
                    acc[i][j] = __builtin_amdgcn_mfma_f32_16x16x32_f16(af[i], bf[j], acc[i][j], 0, 0, 0);
        }
        // write next tile into the other buffer (prev readers of it are done)
        if (t < 3) {
            *(f16x8*)(smem + nb + xs0) = x0;  *(f16x8*)(smem + nb + xs1) = x1;
            *(f16x8*)(smem + nb + wl0) = w0;  *(f16x8*)(smem + nb + wl1) = w1;
            *(f16x8*)(smem + nb + wl2) = w2;  *(f16x8*)(smem + nb + wl3) = w3;
        }
        __syncthreads();
    }

    // ---- epilogue: per 16-row group, LDS transpose + f16 store + fused dots ----
    const int er = tid >> 5;          // 0..15
    const int ec = tid & 31;          // 0..31
    for (int g = 0; g < 8; ++g) {
        if (wr == (g >> 2)) {
            const int i = g & 3;
#pragma unroll
            for (int j = 0; j < 4; ++j) {
                const int col = wc * 64 + j * 16 + ln;
#pragma unroll
                for (int q = 0; q < 4; ++q)
                    Es[kq * 4 + q][col] = acc[i][j][q];
            }
        }
        __syncthreads();
        const int grow = m0 + g * 16 + er;
        const int c0 = ec * 8;
        f32x4 v0 = *(const f32x4*)&Es[er][c0];
        f32x4 v1 = *(const f32x4*)&Es[er][c0 + 4];
        f16x8 ho = {(_Float16)v0[0], (_Float16)v0[1], (_Float16)v0[2], (_Float16)v0[3],
                    (_Float16)v1[0], (_Float16)v1[1], (_Float16)v1[2], (_Float16)v1[3]};
        *(f16x8*)&Hout[(size_t)grow * 256 + c0] = ho;

        f32x4 al0 = *(const f32x4*)&avec[c0];
        f32x4 al1 = *(const f32x4*)&avec[c0 + 4];
        f32x4 ah0 = *(const f32x4*)&avec[256 + c0];
        f32x4 ah1 = *(const f32x4*)&avec[256 + c0 + 4];
        float d0 = v0[0]*al0[0] + v0[1]*al0[1] + v0[2]*al0[2] + v0[3]*al0[3]
                 + v1[0]*al1[0] + v1[1]*al1[1] + v1[2]*al1[2] + v1[3]*al1[3];
        float d1 = v0[0]*ah0[0] + v0[1]*ah0[1] + v0[2]*ah0[2] + v0[3]*ah0[3]
                 + v1[0]*ah1[0] + v1[1]*ah1[1] + v1[2]*ah1[2] + v1[3]*ah1[3];
#pragma unroll
        for (int d = 16; d; d >>= 1) {
            d0 += __shfl_xor(d0, d);
            d1 += __shfl_xor(d1, d);
        }
        if (ec == 0) { si[grow] = d0; sj[grow] = d1; }
        __syncthreads();
    }
}

// ------------------------- edge preprocessing ------------------------------

__global__ void zero_int(int* p, int n)
{
    int i = blockIdx.x * blockDim.x + threadIdx.x;
    if (i < n) p[i] = 0;
}

__global__ void hist_kernel(const int* __restrict__ dst, int* __restrict__ cnt, int E)
{
    int e = blockIdx.x * blockDim.x + threadIdx.x;
    if (e < E) atomicAdd(&cnt[dst[e]], 1);
}

__global__ __launch_bounds__(1024) void scan_part(const int* __restrict__ cnt,
                                                  int* __restrict__ off,
                                                  int* __restrict__ bsum)
{
    __shared__ int buf[1024];
    const int tid = threadIdx.x;
    const int g = blockIdx.x * 1024 + tid;
    int v = cnt[g];
    buf[tid] = v;
    __syncthreads();
#pragma unroll
    for (int d = 1; d < 1024; d <<= 1) {
        int t = (tid >= d) ? buf[tid - d] : 0;
        __syncthreads();
        buf[tid] += t;
        __syncthreads();
    }
    off[g] = buf[tid] - v;                      // local exclusive
    if (tid == 1023) bsum[blockIdx.x] = buf[1023];
}

__global__ void scan_bsum(int* bsum, int nb)
{
    __shared__ int b[64];
    const int tid = threadIdx.x;                // 64 threads
    b[tid] = (tid < nb) ? bsum[tid] : 0;
    __syncthreads();
    if (tid == 0) {
        int a = 0;
        for (int i = 0; i < nb; ++i) { int t = b[i]; b[i] = a; a += t; }
    }
    __syncthreads();
    if (tid < nb) bsum[tid] = b[tid];
}

__global__ __launch_bounds__(1024) void scan_add(const int* __restrict__ bsum,
                                                 int* __restrict__ off,
                                                 int* __restrict__ cursor,
                                                 int NT, int E)
{
    const int tid = threadIdx.x;
    const int g = blockIdx.x * 1024 + tid;
    int v = off[g] + bsum[blockIdx.x];
    off[g] = v;
    cursor[g] = v;
    if (g == 0) off[NT] = E;
}

__global__ void scatter_kernel(const int* __restrict__ src,
                               const int* __restrict__ dst,
                               int* __restrict__ cursor,
                               int* __restrict__ ssrc, int E)
{
    int e = blockIdx.x * blockDim.x + threadIdx.x;
    if (e < E) {
        int p = atomicAdd(&cursor[dst[e]], 1);
        ssrc[p] = src[e];
    }
}

// ------------------------- per-node softmax + aggregate --------------------
// One wave per node. Fast path (deg<=64): lane=edge score+softmax in one pass,
// then x4-unrolled row gather with readlane-broadcast (src,weight).
// F16OUT=1: write f16 (next layer's GEMM input). F16OUT=0: write f32 (d_out).

__device__ __forceinline__ float bcast_f(float x, int l)
{
    return __uint_as_float(__builtin_amdgcn_readlane(__float_as_uint(x), l));
}

template <int F16OUT>
__global__ __launch_bounds__(256) void aggregate(const _Float16* __restrict__ Hh,
                                                 const float* __restrict__ si,
                                                 const float* __restrict__ sj,
                                                 const int* __restrict__ off,
                                                 const int* __restrict__ ssrc,
                                                 void* __restrict__ outv,
                                                 int n_nodes)
{
    const int v = (blockIdx.x * 256 + threadIdx.x) >> 6;   // one wave per node
    const int lane = threadIdx.x & 63;
    if (v >= n_nodes) return;

    const int e0 = off[v], e1 = off[v + 1];
    const int deg = e1 - e0;
    f32x4 acc = {0.f, 0.f, 0.f, 0.f};

    if (deg > 0 && deg <= 64) {
        const float siv = si[v];
        // edge-parallel score: lane l owns edge e0+l
        const int idx = e0 + lane;
        const bool on = idx < e1;
        int s = 0;
        float scv = -1e30f;
        if (on) {
            s = ssrc[idx];
            float t = siv + sj[s];
            scv = (t >= 0.f) ? t : 0.2f * t;
        }
        float m = scv;
#pragma unroll
        for (int d = 32; d; d >>= 1) m = fmaxf(m, __shfl_xor(m, d));
        float wv = on ? __expf(scv - m) : 0.f;
        float den = wv;
#pragma unroll
        for (int d = 32; d; d >>= 1) den += __shfl_xor(den, d);

        // column-parallel gather: lane covers cols [lane*4, lane*4+4)
        const int c4 = lane * 4;
        for (int eo = 0; eo < deg; eo += 4) {
            const int l1 = (eo + 1 < 63) ? eo + 1 : 63;
            const int l2 = (eo + 2 < 63) ? eo + 2 : 63;
            const int l3 = (eo + 3 < 63) ? eo + 3 : 63;
            const int s0 = __builtin_amdgcn_readlane(s, eo);
            const int s1 = __builtin_amdgcn_readlane(s, l1);
            const int s2 = __builtin_amdgcn_readlane(s, l2);
            const int s3 = __builtin_amdgcn_readlane(s, l3);
            const float w0 = bcast_f(wv, eo);
            const float w1 = bcast_f(wv, l1);
            const float w2 = bcast_f(wv, l2);
            const float w3 = bcast_f(wv, l3);
            // 4 independent 512B row loads in flight
            const f16x4 v0 = *(const f16x4*)&Hh[(size_t)s0 * 256 + c4];
            const f16x4 v1 = *(const f16x4*)&Hh[(size_t)s1 * 256 + c4];
            const f16x4 v2 = *(const f16x4*)&Hh[(size_t)s2 * 256 + c4];
            const f16x4 v3 = *(const f16x4*)&Hh[(size_t)s3 * 256 + c4];
#pragma unroll
            for (int q = 0; q < 4; ++q)
                acc[q] += w0 * (float)v0[q] + w1 * (float)v1[q]
                        + w2 * (float)v2[q] + w3 * (float)v3[q];
        }
        const float inv = 1.f / (den * (float)deg);
#pragma unroll
        for (int q = 0; q < 4; ++q) acc[q] *= inv;
    } else if (deg > 64) {
        // generic fallback (rare): 3-pass lane-strided
        const float siv = si[v];
        float m = -1e30f;
        for (int b = e0 + lane; b < e1; b += 64) {
            float t = siv + sj[ssrc[b]];
            t = (t >= 0.f) ? t : 0.2f * t;
            m = fmaxf(m, t);
        }
#pragma unroll
        for (int d = 32; d; d >>= 1) m = fmaxf(m, __shfl_xor(m, d));
        float den = 0.f;
        for (int b = e0 + lane; b < e1; b += 64) {
            float t = siv + sj[ssrc[b]];
            t = (t >= 0.f) ? t : 0.2f * t;
            den += __expf(t - m);
        }
#pragma unroll
        for (int d = 32; d; d >>= 1) den += __shfl_xor(den, d);
        for (int e = e0; e < e1; ++e) {
            const int s = ssrc[e];
            float t = siv + sj[s];
            t = (t >= 0.f) ? t : 0.2f * t;
            const float wgt = __expf(t - m);
            const f16x4 hv = *(const f16x4*)&Hh[(size_t)s * 256 + lane * 4];
#pragma unroll
            for (int q = 0; q < 4; ++q) acc[q] += wgt * (float)hv[q];
        }
        const float inv = 1.f / (den * (float)deg);
#pragma unroll
        for (int q = 0; q < 4; ++q) acc[q] *= inv;
    }

    // ELU + store
    float4 o;
    o.x = (acc[0] > 0.f) ? acc[0] : (__expf(acc[0]) - 1.f);
    o.y = (acc[1] > 0.f) ? acc[1] : (__expf(acc[1]) - 1.f);
    o.z = (acc[2] > 0.f) ? acc[2] : (__expf(acc[2]) - 1.f);
    o.w = (acc[3] > 0.f) ? acc[3] : (__expf(acc[3]) - 1.f);
    if (F16OUT) {
        f16x4 oh = {(_Float16)o.x, (_Float16)o.y, (_Float16)o.z, (_Float16)o.w};
        *(f16x4*)&((_Float16*)outv)[(size_t)v * 256 + lane * 4] = oh;
    } else {
        *(float4*)&((float*)outv)[(size_t)v * 256 + lane * 4] = o;
    }
}

// ---------------------------------------------------------------------------

extern "C" void kernel_launch(void* const* d_in, const int* in_sizes, int n_in,
                              void* d_out, int out_size, void* d_ws, size_t ws_size,
                              hipStream_t stream)
{
    const float* x0 = (const float*)d_in[0];
    const int*   ei = (const int*)d_in[1];      // (2,E) int32: row0=src, row1=dst
    const float* Ws[3] = {(const float*)d_in[2], (const float*)d_in[4], (const float*)d_in[6]};
    const float* as[3] = {(const float*)d_in[3], (const float*)d_in[5], (const float*)d_in[7]};
    float* out = (float*)d_out;

    const int NT = in_sizes[0] / 256;   // 32768
    const int E  = in_sizes[1] / 2;     // 262144
    const int* srcI = ei;
    const int* dstI = ei + E;

    // workspace layout (~34 MB)
    _Float16* Hh = (_Float16*)d_ws;                 // NT*256 f16
    _Float16* Xh = Hh + (size_t)NT * 256;           // NT*256 f16 (layer input)
    float* si    = (float*)(Xh + (size_t)NT * 256);
    float* sj    = si + NT;
    int* cnt     = (int*)(sj + NT);
    int* off     = cnt + NT;            // NT+1 entries
    int* cursor  = off + NT + 1;
    int* ssrc    = cursor + NT;         // E entries
    int* bsum    = ssrc + E;            // 32 entries (round up 64)
    _Float16* Wh = (_Float16*)(((uintptr_t)(bsum + 64) + 255) & ~(uintptr_t)255);

    // all f32->f16 conversions in one launch (x0 then W0|W1|W2)
    const int nx = NT * 256;
    convert_all<<<(nx + 3 * 65536) / 2048, 256, 0, stream>>>(x0, Xh, nx,
                                                             Ws[0], Ws[1], Ws[2], Wh);

    // edge preprocessing (layer-invariant)
    zero_int<<<(NT + 255) / 256, 256, 0, stream>>>(cnt, NT);
    hist_kernel<<<(E + 255) / 256, 256, 0, stream>>>(dstI, cnt, E);
    scan_part<<<NT / 1024, 1024, 0, stream>>>(cnt, off, bsum);
    scan_bsum<<<1, 64, 0, stream>>>(bsum, NT / 1024);
    scan_add<<<NT / 1024, 1024, 0, stream>>>(bsum, off, cursor, NT, E);
    scatter_kernel<<<(E + 255) / 256, 256, 0, stream>>>(srcI, dstI, cursor, ssrc, E);

    for (int l = 0; l < 3; ++l) {
        gemm_f16<<<NT / 128, 512, 0, stream>>>(Xh, Wh + (size_t)l * 65536, as[l], Hh, si, sj);
        if (l < 2)
            aggregate<1><<<NT / 4, 256, 0, stream>>>(Hh, si, sj, off, ssrc, (void*)Xh, NT);
        else
            aggregate<0><<<NT / 4, 256, 0, stream>>>(Hh, si, sj, off, ssrc, (void*)out, NT);
    }
}